// Round 2
// baseline (219.410 us; speedup 1.0000x reference)
//
#include <hip/hip_runtime.h>

#define HID 32

// ---- layer-1 edge pass (IN=8): 32-lane group per edge, 4-edge supersteps ----
// Blocked edge ranges per group; src/dst loaded as int4 (4 edges/inst), next
// superstep's indices prefetched a full superstep (~500cy compute) ahead so
// the streaming-load HBM latency (~900cy) is covered per-group (plus 3-4
// waves/SIMD). x-rows for all 4 edges issue at superstep start.
template<bool DO_COUNT>
__global__ __launch_bounds__(256) void edge8_kernel(
    const float* __restrict__ h_in,                 // [N, 8]
    const int* __restrict__ src, const int* __restrict__ dst,
    const float* __restrict__ ea,                   // [E, 4]
    const float* __restrict__ w_mlp,                // [4, 8*HID]
    const float* __restrict__ b_mlp,                // [8*HID]
    float* __restrict__ agg,                        // [N, HID] (pre-zeroed)
    float* __restrict__ cnt,                        // [N] (pre-zeroed)
    int E)
{
    constexpr int IN = 8;
    const int o    = threadIdx.x & 31;              // output channel
    const int grp  = (blockIdx.x * blockDim.x + threadIdx.x) >> 5;
    const int ngrp = (gridDim.x * blockDim.x) >> 5;

    float w0[IN], w1[IN], w2[IN], w3[IN], br[IN];
    #pragma unroll
    for (int i = 0; i < IN; ++i) {
        int c = i * HID + o;                        // coalesced across lanes
        w0[i] = w_mlp[c];
        w1[i] = w_mlp[IN * HID + c];
        w2[i] = w_mlp[2 * IN * HID + c];
        w3[i] = w_mlp[3 * IN * HID + c];
        br[i] = b_mlp[c];
    }

    const int per  = ((E + ngrp - 1) / ngrp + 3) & ~3;   // %4==0 -> int4 loads stay aligned
    const int base = grp * per;
    if (base >= E) return;
    const int count = min(per, E - base);

    int sc[4], dc[4]; float4 ac[4];
    int j = 0;
    if (count >= 4) {
        int4 s4 = *(const int4*)(src + base);
        int4 d4 = *(const int4*)(dst + base);
        sc[0] = s4.x; sc[1] = s4.y; sc[2] = s4.z; sc[3] = s4.w;
        dc[0] = d4.x; dc[1] = d4.y; dc[2] = d4.z; dc[3] = d4.w;
        #pragma unroll
        for (int jj = 0; jj < 4; ++jj)
            ac[jj] = *(const float4*)(ea + (size_t)(base + jj) * 4);

        for (; j + 4 <= count; j += 4) {
            // x-rows for the current 4 edges (uniform per group -> broadcast fetch)
            float4 xv[4][2];
            #pragma unroll
            for (int jj = 0; jj < 4; ++jj)
                #pragma unroll
                for (int q = 0; q < 2; ++q)
                    xv[jj][q] = *(const float4*)(h_in + (size_t)sc[jj] * IN + q * 4);

            // prefetch next superstep's indices + edge attrs (consumed ~500cy later)
            int sn[4], dn[4]; float4 an[4];
            const bool nf = (j + 8 <= count);
            if (nf) {
                int4 s4n = *(const int4*)(src + base + j + 4);
                int4 d4n = *(const int4*)(dst + base + j + 4);
                sn[0] = s4n.x; sn[1] = s4n.y; sn[2] = s4n.z; sn[3] = s4n.w;
                dn[0] = d4n.x; dn[1] = d4n.y; dn[2] = d4n.z; dn[3] = d4n.w;
                #pragma unroll
                for (int jj = 0; jj < 4; ++jj)
                    an[jj] = *(const float4*)(ea + (size_t)(base + j + 4 + jj) * 4);
            }

            // compute + scatter the 4 edges
            #pragma unroll
            for (int jj = 0; jj < 4; ++jj) {
                float acc = 0.f;
                #pragma unroll
                for (int q = 0; q < 2; ++q) {
                    const float xs[4] = { xv[jj][q].x, xv[jj][q].y, xv[jj][q].z, xv[jj][q].w };
                    #pragma unroll
                    for (int j2 = 0; j2 < 4; ++j2) {
                        const int i = q * 4 + j2;
                        float t = fmaf(ac[jj].x, w0[i], br[i]);
                        t = fmaf(ac[jj].y, w1[i], t);
                        t = fmaf(ac[jj].z, w2[i], t);
                        t = fmaf(ac[jj].w, w3[i], t);
                        t = fmaxf(t, 0.f);
                        acc = fmaf(xs[j2], t, acc);
                    }
                }
                atomicAdd(agg + (size_t)dc[jj] * HID + o, acc);
                if (DO_COUNT && o == 0) atomicAdd(cnt + dc[jj], 1.0f);
            }
            if (nf) {
                #pragma unroll
                for (int jj = 0; jj < 4; ++jj) { sc[jj] = sn[jj]; dc[jj] = dn[jj]; ac[jj] = an[jj]; }
            }
        }
    }
    // generic tail (never runs at E=100000 with this grid, kept for safety)
    for (; j < count; ++j) {
        const int e = base + j;
        const int s = src[e], d = dst[e];
        float4 a = *(const float4*)(ea + (size_t)e * 4);
        float acc = 0.f;
        #pragma unroll
        for (int q = 0; q < 2; ++q) {
            float4 xq = *(const float4*)(h_in + (size_t)s * IN + q * 4);
            const float xs[4] = { xq.x, xq.y, xq.z, xq.w };
            #pragma unroll
            for (int j2 = 0; j2 < 4; ++j2) {
                const int i = q * 4 + j2;
                float t = fmaf(a.x, w0[i], br[i]);
                t = fmaf(a.y, w1[i], t);
                t = fmaf(a.z, w2[i], t);
                t = fmaf(a.w, w3[i], t);
                t = fmaxf(t, 0.f);
                acc = fmaf(xs[j2], t, acc);
            }
        }
        atomicAdd(agg + (size_t)d * HID + o, acc);
        if (DO_COUNT && o == 0) atomicAdd(cnt + d, 1.0f);
    }
}

// ---- layers 2/3 edge pass (IN=32): 64-lane wave per edge (o = lane&31,
// half = lane>>5 owns 16 input channels), 4-edge supersteps as above.
// Per-lane weight state 80 VGPRs; superstep compute ~850cy covers the HBM
// stream latency of the next superstep's index prefetch within one wave.
__global__ __launch_bounds__(256) void edge32_kernel(
    const float* __restrict__ h_in,                 // [N, 32]
    const int* __restrict__ src, const int* __restrict__ dst,
    const float* __restrict__ ea,                   // [E, 4]
    const float* __restrict__ w_mlp,                // [4, 32*HID]
    const float* __restrict__ b_mlp,                // [32*HID]
    float* __restrict__ agg,                        // [N, HID] (pre-zeroed)
    int E)
{
    constexpr int IN = 32;
    constexpr int IH = 16;                          // input channels per half-wave
    const int lane = threadIdx.x & 63;
    const int o    = lane & 31;
    const int half = lane >> 5;
    const int wave  = (blockIdx.x * blockDim.x + threadIdx.x) >> 6;
    const int nwave = (gridDim.x * blockDim.x) >> 6;

    float w0[IH], w1[IH], w2[IH], w3[IH], br[IH];
    #pragma unroll
    for (int i = 0; i < IH; ++i) {
        int c = (half * IH + i) * HID + o;
        w0[i] = w_mlp[c];
        w1[i] = w_mlp[IN * HID + c];
        w2[i] = w_mlp[2 * IN * HID + c];
        w3[i] = w_mlp[3 * IN * HID + c];
        br[i] = b_mlp[c];
    }

    const int per  = ((E + nwave - 1) / nwave + 3) & ~3;
    const int base = wave * per;
    if (base >= E) return;
    const int count = min(per, E - base);

    int sc[4], dc[4]; float4 ac[4];
    int j = 0;
    if (count >= 4) {
        int4 s4 = *(const int4*)(src + base);
        int4 d4 = *(const int4*)(dst + base);
        sc[0] = s4.x; sc[1] = s4.y; sc[2] = s4.z; sc[3] = s4.w;
        dc[0] = d4.x; dc[1] = d4.y; dc[2] = d4.z; dc[3] = d4.w;
        #pragma unroll
        for (int jj = 0; jj < 4; ++jj)
            ac[jj] = *(const float4*)(ea + (size_t)(base + jj) * 4);

        for (; j + 4 <= count; j += 4) {
            // x half-rows for the current 4 edges (2 addrs/wave -> broadcast fetch)
            float4 xv[4][IH / 4];
            #pragma unroll
            for (int jj = 0; jj < 4; ++jj)
                #pragma unroll
                for (int q = 0; q < IH / 4; ++q)
                    xv[jj][q] = *(const float4*)(h_in + (size_t)sc[jj] * IN + half * IH + q * 4);

            // prefetch next superstep's indices + edge attrs
            int sn[4], dn[4]; float4 an[4];
            const bool nf = (j + 8 <= count);
            if (nf) {
                int4 s4n = *(const int4*)(src + base + j + 4);
                int4 d4n = *(const int4*)(dst + base + j + 4);
                sn[0] = s4n.x; sn[1] = s4n.y; sn[2] = s4n.z; sn[3] = s4n.w;
                dn[0] = d4n.x; dn[1] = d4n.y; dn[2] = d4n.z; dn[3] = d4n.w;
                #pragma unroll
                for (int jj = 0; jj < 4; ++jj)
                    an[jj] = *(const float4*)(ea + (size_t)(base + j + 4 + jj) * 4);
            }

            // compute + scatter
            #pragma unroll
            for (int jj = 0; jj < 4; ++jj) {
                float acc = 0.f;
                #pragma unroll
                for (int q = 0; q < IH / 4; ++q) {
                    const float xs[4] = { xv[jj][q].x, xv[jj][q].y, xv[jj][q].z, xv[jj][q].w };
                    #pragma unroll
                    for (int j2 = 0; j2 < 4; ++j2) {
                        const int i = q * 4 + j2;
                        float t = fmaf(ac[jj].x, w0[i], br[i]);
                        t = fmaf(ac[jj].y, w1[i], t);
                        t = fmaf(ac[jj].z, w2[i], t);
                        t = fmaf(ac[jj].w, w3[i], t);
                        t = fmaxf(t, 0.f);
                        acc = fmaf(xs[j2], t, acc);
                    }
                }
                acc += __shfl_down(acc, 32);        // combine i-halves
                if (lane < 32) atomicAdd(agg + (size_t)dc[jj] * HID + o, acc);
            }
            if (nf) {
                #pragma unroll
                for (int jj = 0; jj < 4; ++jj) { sc[jj] = sn[jj]; dc[jj] = dn[jj]; ac[jj] = an[jj]; }
            }
        }
    }
    // generic tail
    for (; j < count; ++j) {
        const int e = base + j;
        const int s = src[e], d = dst[e];
        float4 a = *(const float4*)(ea + (size_t)e * 4);
        float acc = 0.f;
        #pragma unroll
        for (int q = 0; q < IH / 4; ++q) {
            float4 xq = *(const float4*)(h_in + (size_t)s * IN + half * IH + q * 4);
            const float xs[4] = { xq.x, xq.y, xq.z, xq.w };
            #pragma unroll
            for (int j2 = 0; j2 < 4; ++j2) {
                const int i = q * 4 + j2;
                float t = fmaf(a.x, w0[i], br[i]);
                t = fmaf(a.y, w1[i], t);
                t = fmaf(a.z, w2[i], t);
                t = fmaf(a.w, w3[i], t);
                t = fmaxf(t, 0.f);
                acc = fmaf(xs[j2], t, acc);
            }
        }
        acc += __shfl_down(acc, 32);
        if (lane < 32) atomicAdd(agg + (size_t)d * HID + o, acc);
    }
}

// ---- node update: h_out = relu(agg/max(cnt,1) + x@root + bias); optionally re-zero agg ----
template<int IN, bool ZERO_AGG>
__global__ __launch_bounds__(256) void node_kernel(
    const float* __restrict__ x_in,                 // [N, IN]
    float* __restrict__ agg,                        // [N, HID]
    const float* __restrict__ cnt,                  // [N]
    const float* __restrict__ root,                 // [IN, HID]
    const float* __restrict__ bias,                 // [HID]
    float* __restrict__ h_out,                      // [N, HID]
    int N)
{
    int idx = blockIdx.x * blockDim.x + threadIdx.x;
    int v = idx >> 5, o = idx & 31;
    if (v >= N) return;
    float r = bias[o];
    const float* xv = x_in + (size_t)v * IN;
    #pragma unroll
    for (int i = 0; i < IN; ++i)
        r = fmaf(xv[i], root[i * HID + o], r);      // root read coalesced across lanes
    float m = agg[(size_t)v * HID + o] / fmaxf(cnt[v], 1.0f);
    if (ZERO_AGG) agg[(size_t)v * HID + o] = 0.f;   // ready for next layer's edge pass
    h_out[(size_t)v * HID + o] = fmaxf(m + r, 0.f);
}

// ---- fused conv3 node update + output head (h3 never materialized) ----
__global__ __launch_bounds__(256) void node_head_kernel(
    const float* __restrict__ x_in,                 // h2 [N, HID]
    const float* __restrict__ agg,                  // [N, HID]
    const float* __restrict__ cnt,                  // [N]
    const float* __restrict__ root,                 // [HID, HID]
    const float* __restrict__ bias,                 // [HID]
    const float* __restrict__ w1, const float* __restrict__ b1,  // [HID,HID],[HID]
    const float* __restrict__ w2, const float* __restrict__ b2,  // [HID,1],[1]
    float* __restrict__ out, int N)
{
    int idx = blockIdx.x * blockDim.x + threadIdx.x;
    int v = idx >> 5, o = idx & 31;
    if (v >= N) return;
    float r = bias[o];
    const float* xv = x_in + (size_t)v * HID;
    #pragma unroll
    for (int i = 0; i < HID; ++i)
        r = fmaf(xv[i], root[i * HID + o], r);
    float m = agg[(size_t)v * HID + o] / fmaxf(cnt[v], 1.0f);
    float h = fmaxf(m + r, 0.f);                    // h3[v][o], lane-resident

    float t = b1[o];
    #pragma unroll
    for (int i = 0; i < HID; ++i)
        t = fmaf(__shfl(h, i, 32), w1[i * HID + o], t);
    t = fmaxf(t, 0.f) * w2[o];
    #pragma unroll
    for (int dd = 16; dd > 0; dd >>= 1)
        t += __shfl_down(t, dd, 32);
    if (o == 0) out[v] = t + b2[0];
}

extern "C" void kernel_launch(void* const* d_in, const int* in_sizes, int n_in,
                              void* d_out, int out_size, void* d_ws, size_t ws_size,
                              hipStream_t stream)
{
    const float* x      = (const float*)d_in[0];
    const int*   ei     = (const int*)d_in[1];     // [2, E] int32
    const float* ea     = (const float*)d_in[2];
    const float* w_mlp1 = (const float*)d_in[3];
    const float* b_mlp1 = (const float*)d_in[4];
    const float* root1  = (const float*)d_in[5];
    const float* bias1  = (const float*)d_in[6];
    const float* w_mlp2 = (const float*)d_in[7];
    const float* b_mlp2 = (const float*)d_in[8];
    const float* root2  = (const float*)d_in[9];
    const float* bias2  = (const float*)d_in[10];
    const float* w_mlp3 = (const float*)d_in[11];
    const float* b_mlp3 = (const float*)d_in[12];
    const float* root3  = (const float*)d_in[13];
    const float* bias3  = (const float*)d_in[14];
    const float* w_out1 = (const float*)d_in[15];
    const float* b_out1 = (const float*)d_in[16];
    const float* w_out2 = (const float*)d_in[17];
    const float* b_out2 = (const float*)d_in[18];

    const int NODE_IN = 8;
    const int N = in_sizes[0] / NODE_IN;            // 25000
    const int E = in_sizes[2] / 4;                  // 100000
    const int* src = ei;
    const int* dst = ei + E;

    // workspace carve-up: cnt and agg contiguous so ONE memset zeroes both
    char* ws = (char*)d_ws;
    size_t off = 0;
    auto carve = [&](size_t bytes) {
        char* p = ws + off;
        off += (bytes + 255) & ~(size_t)255;
        return p;
    };
    float* cnt = (float*)carve((size_t)N * 4);
    float* agg = (float*)carve((size_t)N * HID * 4);
    size_t zero_bytes = (size_t)((char*)agg - (char*)cnt) + (size_t)N * HID * 4;
    float* h1  = (float*)carve((size_t)N * HID * 4);
    float* h2  = (float*)carve((size_t)N * HID * 4);
    float* outp = (float*)d_out;

    const int TB = 256;
    const int nodeBlocks = (N * HID + TB - 1) / TB;     // 3125
    // 625 blocks: edge32 -> 2500 waves x 40 edges exactly; edge8 -> 5000 groups x 20 edges exactly
    const int edgeBlocks = 625;

    // 1) zero cnt+agg in one shot
    hipMemsetAsync(cnt, 0, zero_bytes, stream);

    // 2) conv1 edge pass (IN=8) + in-degree count
    edge8_kernel<true><<<edgeBlocks, TB, 0, stream>>>(x, src, dst, ea, w_mlp1, b_mlp1, agg, cnt, E);
    // 3) conv1 node update, re-zero agg for conv2
    node_kernel<8, true><<<nodeBlocks, TB, 0, stream>>>(x, agg, cnt, root1, bias1, h1, N);

    // 4) conv2 edge pass (IN=32)
    edge32_kernel<<<edgeBlocks, TB, 0, stream>>>(h1, src, dst, ea, w_mlp2, b_mlp2, agg, E);
    // 5) conv2 node update, re-zero agg for conv3
    node_kernel<32, true><<<nodeBlocks, TB, 0, stream>>>(h1, agg, cnt, root2, bias2, h2, N);

    // 6) conv3 edge pass (IN=32)
    edge32_kernel<<<edgeBlocks, TB, 0, stream>>>(h2, src, dst, ea, w_mlp3, b_mlp3, agg, E);
    // 7) conv3 node update fused with output head
    node_head_kernel<<<nodeBlocks, TB, 0, stream>>>(h2, agg, cnt, root3, bias3,
                                                    w_out1, b_out1, w_out2, b_out2, outp, N);
}